// Round 15
// baseline (155.277 us; speedup 1.0000x reference)
//
#include <hip/hip_runtime.h>
#include <stdint.h>

#define NPRIOR 8400
#define NB 32
#define NCLS 80
#define KTOP 1000
#define CAP 8400   // worst-case candidates; never overflows
#define CPAD 16    // ints per counter slot (64B) -> no same-line atomic pileup
#define PCH 8      // class chunks
#define CPC 10     // classes per chunk (PCH*CPC == NCLS)

typedef unsigned long long u64;

// Bit-exact replica of numpy's float32 SIMD exp (Cephes-style, FMA path).
__device__ __forceinline__ float exp_np(float x) {
#pragma clang fp contract(off)
    if (x > 88.72283935546875f) return __builtin_huge_valf();
    if (x < -87.3365478515625f) return 0.0f;
    float q = rintf(x * 1.442695040f);          // v_rndne: round-nearest-even
    float r = fmaf(q, -6.93145752e-1f, x);      // hi split
    r = fmaf(q, -1.42860677e-6f, r);            // lo split
    float p = fmaf(1.9875691500e-4f, r, 1.3981999507e-3f);
    p = fmaf(p, r, 8.3334519073e-3f);
    p = fmaf(p, r, 4.1665795894e-2f);
    p = fmaf(p, r, 1.6666665459e-1f);
    p = fmaf(p, r, 5.0000001201e-1f);
    float r2 = r * r;
    p = fmaf(p, r2, r);
    p = p + 1.0f;
    return ldexpf(p, (int)q);                   // exact 2^q scaling
}
__device__ __forceinline__ float sigm_np(float x) {
#pragma clang fp contract(off)
    float t = exp_np(-x);
    return 1.0f / (1.0f + t);
}

__device__ __forceinline__ void level_of(int n, int& W, int& s, int& loc) {
    if (n < 6400)      { W = 80; s = 8;  loc = n; }
    else if (n < 8000) { W = 40; s = 16; loc = n - 6400; }
    else               { W = 20; s = 32; loc = n - 8000; }
}

__device__ float4 decode32(int b, int n,
                           const float* bb0, const float* bb1, const float* bb2) {
#pragma clang fp contract(off)
    int W, s, loc; level_of(n, W, s, loc);
    const float* bb = (s == 8) ? bb0 : (s == 16) ? bb1 : bb2;
    int hw = W * W;
    int y = loc / W, x = loc - y * W;
    const float* bp = bb + (size_t)b * 4 * hw + y * W + x;
    float fs = (float)s;
    float cx = (float)x * fs, cy = (float)y * fs;
    float xc = bp[0] * fs + cx;
    float yc = bp[hw] * fs + cy;
    float wv = exp_np(bp[2 * hw]) * fs;
    float hv = exp_np(bp[3 * hw]) * fs;
    float wv2 = wv * 0.5f, hv2 = hv * 0.5f;
    float4 r;
    r.x = xc - wv2;
    r.y = yc - hv2;
    r.z = xc + wv2;
    r.w = yc + hv2;
    return r;
}

// order-preserving f32 -> u32 (total order matches float compare)
__device__ __forceinline__ unsigned flt2ord(float f) {
    unsigned u = __float_as_uint(f);
    return u ^ ((u >> 31) ? 0xffffffffu : 0x80000000u);
}
__device__ __forceinline__ float ord2flt(unsigned u) {
    u ^= ((u >> 31) ? 0x80000000u : 0xffffffffu);
    return __uint_as_float(u);
}
// pack (ord(logit)<<32)|~class : u64 max == (max logit, first/smallest class)
__device__ __forceinline__ u64 packlc(float l, int c) {
    return ((u64)flt2ord(l) << 32) | (unsigned)(~(unsigned)c);
}

// ---- Kernel A1: per-chunk logit (first-max, runner-up) — NO transcendentals ----
__global__ void __launch_bounds__(256) score1_k(
    const float* __restrict__ cls0, const float* __restrict__ cls1, const float* __restrict__ cls2,
    u64* __restrict__ part, float* __restrict__ part2, int* __restrict__ zeroed)
{
    int b = blockIdx.z, ch = blockIdx.y;
    // zero cnts/maxbits for this image (read only by later kernels)
    if (blockIdx.x == 0 && ch == 0 && threadIdx.x == 0) {
        zeroed[b * CPAD] = 0;                    // cnts
        zeroed[NB * CPAD + b * CPAD] = 0;        // maxbits
    }
    int g = blockIdx.x * 256 + threadIdx.x;
    if (g >= NPRIOR / 4) return;
    int n0 = g * 4;
    int W, s, loc; level_of(n0, W, s, loc);
    const float* cls = (s == 8) ? cls0 : (s == 16) ? cls1 : cls2;
    int hw = W * W;
    int y = loc / W, x = loc - y * W;
    const float* cp = cls + (size_t)b * NCLS * hw + y * W + x;   // 16B aligned

    int c0 = ch * CPC;
    float4 v = *(const float4*)(cp + (size_t)c0 * hw);
    float M[4]  = {v.x, v.y, v.z, v.w};
    float S2[4] = {-3.4e38f, -3.4e38f, -3.4e38f, -3.4e38f};
    int   I[4]  = {c0, c0, c0, c0};
#pragma unroll
    for (int cc = 1; cc < CPC; ++cc) {
        int c = c0 + cc;
        v = *(const float4*)(cp + (size_t)c * hw);
        float l[4] = {v.x, v.y, v.z, v.w};
#pragma unroll
        for (int e = 0; e < 4; ++e) {
            if (l[e] > M[e]) { S2[e] = M[e]; M[e] = l[e]; I[e] = c; }
            else             { S2[e] = fmaxf(S2[e], l[e]); }
        }
    }
    u64* p = part + ((size_t)ch * NB + b) * NPRIOR + n0;
    float* p2 = part2 + ((size_t)ch * NB + b) * NPRIOR + n0;
#pragma unroll
    for (int e = 0; e < 4; ++e) { p[e] = packlc(M[e], I[e]); p2[e] = S2[e]; }
}

// ---- Kernel A2: STREAMING chunk merge + sigmoid fast-path + compaction ----
// No per-thread arrays -> no scratch spill (round-14 lesson: VGPR 56 + spilled
// P[8][4]/Z[8][4] made this kernel 65us at 1.9% occupancy).
__global__ void __launch_bounds__(256) score2_k(
    const float* __restrict__ cls0, const float* __restrict__ cls1, const float* __restrict__ cls2,
    const float* __restrict__ ob0, const float* __restrict__ ob1, const float* __restrict__ ob2,
    const u64* __restrict__ part, const float* __restrict__ part2,
    float* __restrict__ sc, int* __restrict__ labels,
    u64* __restrict__ keys, int* __restrict__ cnts, int* __restrict__ rankbuf)
{
#pragma clang fp contract(off)
    int b = blockIdx.y;
    int g = blockIdx.x * 256 + threadIdx.x;
    if (g >= NPRIOR / 4) return;                 // inactive lanes drop from ballots
    int n0 = g * 4;
    int W, s, loc; level_of(n0, W, s, loc);
    const float* cls = (s == 8) ? cls0 : (s == 16) ? cls1 : cls2;
    const float* ob  = (s == 8) ? ob0  : (s == 16) ? ob1  : ob2;
    int hw = W * W;
    int y = loc / W, x = loc - y * W;

    // running state per element: best pack, its in-chunk runner-up Z,
    // and max-of-other-chunks' M. Streaming => ~16 VGPRs, no arrays.
    const u64* pp0 = part + ((size_t)0 * NB + b) * NPRIOR + n0;
    const float* pz0 = part2 + ((size_t)0 * NB + b) * NPRIOR + n0;
    u64 bp0 = pp0[0], bp1 = pp0[1], bp2 = pp0[2], bp3 = pp0[3];
    float bz0 = pz0[0], bz1 = pz0[1], bz2 = pz0[2], bz3 = pz0[3];
    float m20 = -3.4e38f, m21 = -3.4e38f, m22 = -3.4e38f, m23 = -3.4e38f;
#pragma unroll
    for (int ch = 1; ch < PCH; ++ch) {
        const u64* pp = part + ((size_t)ch * NB + b) * NPRIOR + n0;
        const float* pz = part2 + ((size_t)ch * NB + b) * NPRIOR + n0;
        u64 t; float z;
        t = pp[0]; z = pz[0];
        if (t > bp0) { m20 = fmaxf(m20, ord2flt((unsigned)(bp0 >> 32))); bp0 = t; bz0 = z; }
        else         { m20 = fmaxf(m20, ord2flt((unsigned)(t >> 32))); }
        t = pp[1]; z = pz[1];
        if (t > bp1) { m21 = fmaxf(m21, ord2flt((unsigned)(bp1 >> 32))); bp1 = t; bz1 = z; }
        else         { m21 = fmaxf(m21, ord2flt((unsigned)(t >> 32))); }
        t = pp[2]; z = pz[2];
        if (t > bp2) { m22 = fmaxf(m22, ord2flt((unsigned)(bp2 >> 32))); bp2 = t; bz2 = z; }
        else         { m22 = fmaxf(m22, ord2flt((unsigned)(t >> 32))); }
        t = pp[3]; z = pz[3];
        if (t > bp3) { m23 = fmaxf(m23, ord2flt((unsigned)(bp3 >> 32))); bp3 = t; bz3 = z; }
        else         { m23 = fmaxf(m23, ord2flt((unsigned)(t >> 32))); }
    }

    float tMv[4]; int labv[4];
    u64 bestv[4] = {bp0, bp1, bp2, bp3};
    float m2v[4] = {fmaxf(m20, bz0), fmaxf(m21, bz1), fmaxf(m22, bz2), fmaxf(m23, bz3)};
#pragma unroll
    for (int e = 0; e < 4; ++e) {
        float M = ord2flt((unsigned)(bestv[e] >> 32));
        int lab = (int)(~(unsigned)(bestv[e] & 0xffffffffull));
        float tM = sigm_np(M);
        // fast-path guard: sigmoid order provably follows logit order when
        // gap * e^{-max|logit|} > 1.6e-5  (deriv >= e^{-|x|}/4; err < 1e-6, 4x margin)
        float gap = M - m2v[e];
        float mx = fmaxf(fabsf(M), fabsf(m2v[e]));
        bool safe = (gap * exp_np(-mx)) > 1.6e-5f;
        if (!safe) {                              // rare exact fallback
            const float* cpe = cls + (size_t)b * NCLS * hw + y * W + x + e;
            tM = sigm_np(cpe[0]); lab = 0;
            for (int c = 1; c < NCLS; ++c) {
                float t = sigm_np(cpe[(size_t)c * hw]);
                if (t > tM) { tM = t; lab = c; }
            }
        }
        tMv[e] = tM; labv[e] = lab;
    }

    float4 o = *(const float4*)(ob + (size_t)b * hw + y * W + x);
    float so[4] = {sigm_np(o.x), sigm_np(o.y), sigm_np(o.z), sigm_np(o.w)};
    float scv[4];
#pragma unroll
    for (int e = 0; e < 4; ++e) {
        float sv = tMv[e] * so[e];
        scv[e] = (sv >= 0.65f) ? sv : 0.0f;
    }
    *(float4*)(sc + (size_t)b * NPRIOR + n0) = make_float4(scv[0], scv[1], scv[2], scv[3]);
    *(int4*)(labels + (size_t)b * NPRIOR + n0) = make_int4(labv[0], labv[1], labv[2], labv[3]);

    // wave-aggregated compaction (order-free; ranking restores stable order)
    int lane = threadIdx.x & 63;
#pragma unroll
    for (int e = 0; e < 4; ++e) {
        float se = scv[e];
        bool val = se > 0.0f;
        u64 mb = __ballot(val);
        if (mb) {                                    // wave-uniform branch
            int lead = (int)__builtin_ctzll(mb);
            int base = 0;
            if (lane == lead) base = atomicAdd(&cnts[b * CPAD], (int)__popcll(mb));
            base = __shfl(base, lead);
            if (val) {
                int myoff = (int)__popcll(mb & ((1ull << lane) - 1ull));
                int pos = base + myoff;
                keys[(size_t)b * CAP + pos] =
                    ((u64)__float_as_uint(se) << 32) | (unsigned)(~(unsigned)(n0 + e));
                rankbuf[(size_t)b * CAP + pos] = 0;   // replaces the big memset
            }
        }
    }
}

// ---- Kernel B1: 2D-tiled all-pairs partial rank (atomicAdd accumulate) ----
__global__ void __launch_bounds__(256) rank_part(
    const u64* __restrict__ keys, const int* __restrict__ cnts,
    int* __restrict__ rankbuf)
{
    int b = blockIdx.y, tid = threadIdx.x;
    int cn = min(cnts[b * CPAD], CAP);
    int nt = (cn + 255) >> 8;                    // tiles per dimension
    int ntt = nt * nt;
    const u64* keyimg = keys + (size_t)b * CAP;
    int lane = tid & 63;

    for (int t = blockIdx.x; t < ntt; t += gridDim.x) {
        int it = t / nt, jt = t - it * nt;
        int i = it * 256 + tid;
        u64 ki = (i < cn) ? keyimg[i] : ~0ull;   // sentinel: counts stay 0
        int rank = 0;
        int jbase = jt * 256;
        int jend = min(jbase + 256, cn);
        for (int jb = jbase; jb < jend; jb += 64) {
            int j = jb + lane;
            u64 kv = (j < cn) ? keyimg[j] : 0ull;   // coalesced, cache-hot
            unsigned lo = (unsigned)kv, hi = (unsigned)(kv >> 32);
            int lim = jend - jb;                     // uniform
#pragma unroll
            for (int l = 0; l < 64; ++l) {
                unsigned jlo = __builtin_amdgcn_readlane(lo, l);
                unsigned jhi = __builtin_amdgcn_readlane(hi, l);
                u64 kj = ((u64)jhi << 32) | jlo;
                rank += (l < lim && kj > ki) ? 1 : 0;
            }
        }
        if (i < cn && rank > 0) atomicAdd(&rankbuf[(size_t)b * CAP + i], rank);
    }
}

// ---- Kernel B2: scatter by rank + decode + housekeeping ----
__global__ void __launch_bounds__(256) scatter_k(
    const u64* __restrict__ keys, const int* __restrict__ cnts,
    const int* __restrict__ rankbuf,
    const float* __restrict__ sc, const int* __restrict__ labels,
    const float* __restrict__ bb0, const float* __restrict__ bb1, const float* __restrict__ bb2,
    float4* __restrict__ sel_box, float* __restrict__ sel_score,
    int* __restrict__ sel_label, int* __restrict__ maxbits, u64* __restrict__ vmask)
{
#pragma clang fp contract(off)
    __shared__ float redbuf[256];
    int b = blockIdx.y, chunk = blockIdx.x, tid = threadIdx.x;
    int cn = min(cnts[b * CPAD], CAP);
    int base = chunk * 256;
    if (chunk != 0 && base >= cn) return;   // housekeeping lives in chunk 0

    const u64* keyimg = keys + (size_t)b * CAP;
    const int* labb = labels + (size_t)b * NPRIOR;
    const float* scb = sc + (size_t)b * NPRIOR;

    int i = base + tid;
    float lmax = 0.0f;
    if (i < cn) {
        int rank = rankbuf[(size_t)b * CAP + i];
        if (rank < KTOP) {
            u64 ki = keyimg[i];
            unsigned n = ~(unsigned)(ki & 0xffffffffull);
            float s = __uint_as_float((unsigned)(ki >> 32));
            float4 bx = decode32(b, (int)n, bb0, bb1, bb2);
            sel_box[(size_t)b * 1024 + rank] = bx;
            sel_score[(size_t)b * 1024 + rank] = s;
            sel_label[(size_t)b * 1024 + rank] = labb[n];
            lmax = fmaxf(fmaxf(fabsf(bx.x), fabsf(bx.y)),
                         fmaxf(fabsf(bx.z), fabsf(bx.w)));
        }
    }

    if (chunk == 0) {
        // rare fill path: fewer than K valid -> lowest-index zero-score priors
        if (cn < KTOP && tid == 0) {
            float lm = 0.0f;
            int r = cn;
            for (int n = 0; n < NPRIOR && r < KTOP; ++n) {
                if (scb[n] == 0.0f) {
                    float4 bx = decode32(b, n, bb0, bb1, bb2);
                    sel_box[(size_t)b * 1024 + r] = bx;
                    sel_score[(size_t)b * 1024 + r] = 0.0f;
                    sel_label[(size_t)b * 1024 + r] = labb[n];
                    lm = fmaxf(lm, fmaxf(fmaxf(fabsf(bx.x), fabsf(bx.y)),
                                         fmaxf(fabsf(bx.z), fabsf(bx.w))));
                    ++r;
                }
            }
            lmax = fmaxf(lmax, lm);
        }
        if (tid < 24) {   // padding rows 1000..1023 (excluded via vmask)
            sel_box[(size_t)b * 1024 + 1000 + tid] = make_float4(0.f, 0.f, 0.f, 0.f);
            sel_score[(size_t)b * 1024 + 1000 + tid] = 0.0f;
            sel_label[(size_t)b * 1024 + 1000 + tid] = 0;
        }
        if (tid < 16) {   // vmask closed form
            int vc = min(cn, KTOP);
            int lo = tid * 64;
            u64 m;
            if (vc >= lo + 64)      m = ~0ull;
            else if (vc <= lo)      m = 0ull;
            else                    m = (1ull << (vc - lo)) - 1ull;
            vmask[b * 16 + tid] = m;
        }
    }

    redbuf[tid] = lmax;
    __syncthreads();
    for (int off = 128; off > 0; off >>= 1) {
        if (tid < off) redbuf[tid] = fmaxf(redbuf[tid], redbuf[tid + off]);
        __syncthreads();
    }
    if (tid == 0) atomicMax(&maxbits[b * CPAD], __float_as_int(redbuf[0]));
}

// ---- Kernel C: ballot-free suppression bitmask, per-lane column ownership ----
__global__ void __launch_bounds__(256) build_mask_T(
    const float4* __restrict__ sel_box, const int* __restrict__ sel_label,
    const int* __restrict__ maxbits, u64* __restrict__ Cmask)
{
#pragma clang fp contract(off)
    __shared__ float4 obr[256];   // offset row boxes for this rg-quad
    __shared__ float arr[256];    // their areas
    int b = blockIdx.y;
    int cg = blockIdx.x & 15, rgq = blockIdx.x >> 4;
    if (rgq * 4 > cg) return;                    // block-uniform triangle skip
    int tid = threadIdx.x, wave = tid >> 6, lane = tid & 63;
    float mc = __int_as_float(maxbits[b * CPAD]) + 1.0f;   // max_coord

    {   // stage rows [rgq*256, rgq*256+256) with class offset + area
        int row = rgq * 256 + tid;
        float4 v = sel_box[(size_t)b * 1024 + row];
        float off = (float)sel_label[(size_t)b * 1024 + row] * mc;
        v.x += off; v.y += off; v.z += off; v.w += off;
        obr[tid] = v;
        arr[tid] = (v.z - v.x) * (v.w - v.y);    // area of OFFSET box (as ref)
    }
    // per-lane column box (registers)
    int col = cg * 64 + lane;
    float4 a = sel_box[(size_t)b * 1024 + col];
    float offc = (float)sel_label[(size_t)b * 1024 + col] * mc;
    a.x += offc; a.y += offc; a.z += offc; a.w += offc;
    float ac = (a.z - a.x) * (a.w - a.y);
    __syncthreads();

    int rg = rgq * 4 + wave;
    if (rg > cg) return;                          // wave-uniform (after barrier)
    int rowbase = rg * 64;
    u64 bits = 0;
#pragma unroll 8
    for (int r = 0; r < 64; ++r) {
        int row = rowbase + r;
        float4 rb = obr[wave * 64 + r];           // broadcast LDS read
        float ra = arr[wave * 64 + r];
        bool pred = false;
        if (row < col && row < KTOP && col < KTOP) {
            float tlx = fmaxf(rb.x, a.x), tly = fmaxf(rb.y, a.y);   // row-first order
            float brx = fminf(rb.z, a.z), bry = fminf(rb.w, a.w);
            float w = fmaxf(brx - tlx, 0.0f), h = fmaxf(bry - tly, 0.0f);
            float inter = w * h;
            float uni = (ra + ac) - inter;        // row-area + col-area, as ref
            float iou = inter / (uni + 1e-6f);
            pred = iou > 0.65f;
        }
        bits |= pred ? (1ull << r) : 0ull;
    }
    Cmask[((size_t)b * 16 + rg) * 1024 + col] = bits;   // 512B coalesced/wave
}

// ---- Kernel D: ballot-fixpoint greedy NMS + output (coalesced Cmask reads) ----
__global__ void __launch_bounds__(64) nms_fixpoint_write(
    const u64* __restrict__ Cmask, const u64* __restrict__ vmask,
    const float4* __restrict__ sel_box, const float* __restrict__ sel_score,
    const int* __restrict__ sel_label, float* __restrict__ out)
{
    int b = blockIdx.x, lane = threadIdx.x;
    const u64* Cimg = Cmask + (size_t)b * 16 * 1024;
    u64 Khist[16];
#pragma unroll
    for (int g = 0; g < 16; ++g) {
        int col = g * 64 + lane;
        bool supp = false;
#pragma unroll
        for (int gp = 0; gp < g; ++gp)
            supp |= (Cimg[(size_t)gp * 1024 + col] & Khist[gp]) != 0ull;
        u64 V = vmask[b * 16 + g] & ~__ballot(supp);
        u64 T = Cimg[(size_t)g * 1024 + col];
        u64 K = V;
        for (int it = 0; it < 64; ++it) {
            u64 Knew = V & ~__ballot((T & K) != 0ull);
            if (Knew == K) break;        // wave-uniform branch
            K = Knew;
        }
        Khist[g] = K;
    }

    const size_t selo = (size_t)b * 1024;
    float* lab_o = out + (size_t)NB * KTOP * 5;
    float* keep_o = lab_o + (size_t)NB * KTOP;
#pragma unroll
    for (int g = 0; g < 16; ++g) {
        int k = g * 64 + lane;
        if (k >= KTOP) break;
        bool fin = (Khist[g] >> lane) & 1ull;
        float4 bx = sel_box[selo + k];
        float s = sel_score[selo + k];
        int lb = sel_label[selo + k];
        size_t o5 = ((size_t)b * KTOP + k) * 5;
        out[o5 + 0] = fin ? bx.x : 0.0f;
        out[o5 + 1] = fin ? bx.y : 0.0f;
        out[o5 + 2] = fin ? bx.z : 0.0f;
        out[o5 + 3] = fin ? bx.w : 0.0f;
        out[o5 + 4] = fin ? s : 0.0f;
        lab_o[b * KTOP + k] = fin ? (float)lb : -1.0f;
        keep_o[b * KTOP + k] = fin ? 1.0f : 0.0f;
    }
}

extern "C" void kernel_launch(void* const* d_in, const int* in_sizes, int n_in,
                              void* d_out, int out_size, void* d_ws, size_t ws_size,
                              hipStream_t stream) {
    const float* cls0 = (const float*)d_in[0];
    const float* cls1 = (const float*)d_in[1];
    const float* cls2 = (const float*)d_in[2];
    const float* bb0  = (const float*)d_in[3];
    const float* bb1  = (const float*)d_in[4];
    const float* bb2  = (const float*)d_in[5];
    const float* ob0  = (const float*)d_in[6];
    const float* ob1  = (const float*)d_in[7];
    const float* ob2  = (const float*)d_in[8];
    float* out = (float*)d_out;

    char* w = (char*)d_ws;
    size_t used = 0;
    auto alloc = [&](size_t bytes) -> void* {
        void* p = (void*)(w + used);
        used += (bytes + 255) & ~(size_t)255;
        return p;
    };
    float* sc        = (float*)alloc((size_t)NB * NPRIOR * 4);
    int* labels      = (int*)alloc((size_t)NB * NPRIOR * 4);
    u64* keys        = (u64*)alloc((size_t)NB * CAP * 8);
    u64* part        = (u64*)alloc((size_t)PCH * NB * NPRIOR * 8);
    float* part2     = (float*)alloc((size_t)PCH * NB * NPRIOR * 4);
    int* zeroed      = (int*)alloc((size_t)2 * NB * CPAD * 4);   // cnts | maxbits
    int* rankbuf     = (int*)alloc((size_t)NB * CAP * 4);
    float4* sel_box  = (float4*)alloc((size_t)NB * 1024 * 16);
    float* sel_score = (float*)alloc((size_t)NB * 1024 * 4);
    int* sel_label   = (int*)alloc((size_t)NB * 1024 * 4);
    u64* vmask       = (u64*)alloc((size_t)NB * 16 * 8);
    u64* Cmask       = (u64*)alloc((size_t)NB * 16 * 1024 * 8);

    if (used > ws_size) return;   // OOB-write guard

    int* cnts = zeroed;
    int* maxbits = zeroed + NB * CPAD;

    score1_k<<<dim3((NPRIOR / 4 + 255) / 256, PCH, NB), 256, 0, stream>>>(
        cls0, cls1, cls2, part, part2, zeroed);
    score2_k<<<dim3((NPRIOR / 4 + 255) / 256, NB), 256, 0, stream>>>(
        cls0, cls1, cls2, ob0, ob1, ob2, part, part2,
        sc, labels, keys, cnts, rankbuf);
    rank_part<<<dim3(64, NB), 256, 0, stream>>>(keys, cnts, rankbuf);
    scatter_k<<<dim3((CAP + 255) / 256, NB), 256, 0, stream>>>(
        keys, cnts, rankbuf, sc, labels, bb0, bb1, bb2,
        sel_box, sel_score, sel_label, maxbits, vmask);
    build_mask_T<<<dim3(64, NB), 256, 0, stream>>>(sel_box, sel_label, maxbits, Cmask);
    nms_fixpoint_write<<<NB, 64, 0, stream>>>(
        Cmask, vmask, sel_box, sel_score, sel_label, out);
}

// Round 16
// 150.022 us; speedup vs baseline: 1.0350x; 1.0350x over previous
//
#include <hip/hip_runtime.h>
#include <stdint.h>

#define NPRIOR 8400
#define NB 32
#define NCLS 80
#define KTOP 1000
#define CAP 8400   // worst-case candidates
#define CPAD 16    // ints per counter slot (64B)
#define NGRP 2100  // NPRIOR/4 groups of 4 priors
#define NBLK 33    // ceil(NGRP/64) blocks per image
#define WCLS 20    // classes per wave (4 waves x 20 = 80)

typedef unsigned long long u64;

// Bit-exact replica of numpy's float32 SIMD exp (Cephes-style, FMA path).
__device__ __forceinline__ float exp_np(float x) {
#pragma clang fp contract(off)
    if (x > 88.72283935546875f) return __builtin_huge_valf();
    if (x < -87.3365478515625f) return 0.0f;
    float q = rintf(x * 1.442695040f);
    float r = fmaf(q, -6.93145752e-1f, x);
    r = fmaf(q, -1.42860677e-6f, r);
    float p = fmaf(1.9875691500e-4f, r, 1.3981999507e-3f);
    p = fmaf(p, r, 8.3334519073e-3f);
    p = fmaf(p, r, 4.1665795894e-2f);
    p = fmaf(p, r, 1.6666665459e-1f);
    p = fmaf(p, r, 5.0000001201e-1f);
    float r2 = r * r;
    p = fmaf(p, r2, r);
    p = p + 1.0f;
    return ldexpf(p, (int)q);
}
__device__ __forceinline__ float sigm_np(float x) {
#pragma clang fp contract(off)
    float t = exp_np(-x);
    return 1.0f / (1.0f + t);
}

__device__ __forceinline__ void level_of(int n, int& W, int& s, int& loc) {
    if (n < 6400)      { W = 80; s = 8;  loc = n; }
    else if (n < 8000) { W = 40; s = 16; loc = n - 6400; }
    else               { W = 20; s = 32; loc = n - 8000; }
}

__device__ float4 decode32(int b, int n,
                           const float* bb0, const float* bb1, const float* bb2) {
#pragma clang fp contract(off)
    int W, s, loc; level_of(n, W, s, loc);
    const float* bb = (s == 8) ? bb0 : (s == 16) ? bb1 : bb2;
    int hw = W * W;
    int y = loc / W, x = loc - y * W;
    const float* bp = bb + (size_t)b * 4 * hw + y * W + x;
    float fs = (float)s;
    float cx = (float)x * fs, cy = (float)y * fs;
    float xc = bp[0] * fs + cx;
    float yc = bp[hw] * fs + cy;
    float wv = exp_np(bp[2 * hw]) * fs;
    float hv = exp_np(bp[3 * hw]) * fs;
    float wv2 = wv * 0.5f, hv2 = hv * 0.5f;
    float4 r;
    r.x = xc - wv2;
    r.y = yc - hv2;
    r.z = xc + wv2;
    r.w = yc + hv2;
    return r;
}

__device__ __forceinline__ unsigned flt2ord(float f) {
    unsigned u = __float_as_uint(f);
    return u ^ ((u >> 31) ? 0xffffffffu : 0x80000000u);
}
__device__ __forceinline__ float ord2flt(unsigned u) {
    u ^= ((u >> 31) ? 0x80000000u : 0xffffffffu);
    return __uint_as_float(u);
}
__device__ __forceinline__ u64 packlc(float l, int c) {
    return ((u64)flt2ord(l) << 32) | (unsigned)(~(unsigned)c);
}

// ---- Kernel A (fused): class-parallel score + label + per-block compaction ----
// 4 waves cover the SAME 64 prior-groups; wave w reduces classes [20w,20w+20).
// Wave 0 merges via LDS, applies the sigmoid fast-path, and compacts valid
// candidates into this block's private keys region (ballot prefix, no atomics).
__global__ void __launch_bounds__(256) score_fused(
    const float* __restrict__ cls0, const float* __restrict__ cls1, const float* __restrict__ cls2,
    const float* __restrict__ ob0,  const float* __restrict__ ob1,  const float* __restrict__ ob2,
    float* __restrict__ sc, int* __restrict__ labels,
    u64* __restrict__ keys_r, int* __restrict__ blkcnt)
{
#pragma clang fp contract(off)
    __shared__ u64 packs[256][4];   // [wave*64+lane][e] : 8KB
    __shared__ float s2sh[256][4];  // 4KB
    int b = blockIdx.y, blk = blockIdx.x;
    int tid = threadIdx.x, wave = tid >> 6, lane = tid & 63;
    int g = blk * 64 + lane;
    bool gvalid = (g < NGRP);
    int n0 = g * 4;

    if (gvalid) {
        int W, s, loc; level_of(n0, W, s, loc);
        const float* cls = (s == 8) ? cls0 : (s == 16) ? cls1 : cls2;
        int hw = W * W;
        int y = loc / W, x = loc - y * W;
        const float* cp = cls + (size_t)b * NCLS * hw + y * W + x;
        int c0 = wave * WCLS;
        float4 v = *(const float4*)(cp + (size_t)c0 * hw);
        float M0 = v.x, M1 = v.y, M2 = v.z, M3 = v.w;
        float S0 = -3.4e38f, S1 = -3.4e38f, S2 = -3.4e38f, S3 = -3.4e38f;
        int I0 = c0, I1 = c0, I2 = c0, I3 = c0;
#pragma unroll
        for (int cc = 1; cc < WCLS; ++cc) {
            int c = c0 + cc;
            v = *(const float4*)(cp + (size_t)c * hw);
            if (v.x > M0) { S0 = M0; M0 = v.x; I0 = c; } else S0 = fmaxf(S0, v.x);
            if (v.y > M1) { S1 = M1; M1 = v.y; I1 = c; } else S1 = fmaxf(S1, v.y);
            if (v.z > M2) { S2 = M2; M2 = v.z; I2 = c; } else S2 = fmaxf(S2, v.z);
            if (v.w > M3) { S3 = M3; M3 = v.w; I3 = c; } else S3 = fmaxf(S3, v.w);
        }
        packs[tid][0] = packlc(M0, I0); s2sh[tid][0] = S0;
        packs[tid][1] = packlc(M1, I1); s2sh[tid][1] = S1;
        packs[tid][2] = packlc(M2, I2); s2sh[tid][2] = S2;
        packs[tid][3] = packlc(M3, I3); s2sh[tid][3] = S3;
    }
    __syncthreads();

    if (wave == 0) {                      // wave-uniform branch; full wave active
        float scv[4]; int labv[4];        // static indexing via full unroll
        if (gvalid) {
            int W, s, loc; level_of(n0, W, s, loc);
            const float* cls = (s == 8) ? cls0 : (s == 16) ? cls1 : cls2;
            const float* ob  = (s == 8) ? ob0  : (s == 16) ? ob1  : ob2;
            int hw = W * W;
            int y = loc / W, x = loc - y * W;
            float4 o = *(const float4*)(ob + (size_t)b * hw + y * W + x);
            float so[4] = {sigm_np(o.x), sigm_np(o.y), sigm_np(o.z), sigm_np(o.w)};
#pragma unroll
            for (int e = 0; e < 4; ++e) {
                u64 bp = packs[lane][e];
                float bz = s2sh[lane][e];
                float m2 = -3.4e38f;
#pragma unroll
                for (int w2 = 1; w2 < 4; ++w2) {
                    u64 t = packs[w2 * 64 + lane][e];
                    float z = s2sh[w2 * 64 + lane][e];
                    if (t > bp) { m2 = fmaxf(m2, ord2flt((unsigned)(bp >> 32))); bp = t; bz = z; }
                    else        { m2 = fmaxf(m2, ord2flt((unsigned)(t >> 32))); }
                }
                m2 = fmaxf(m2, bz);
                float M = ord2flt((unsigned)(bp >> 32));
                int lab = (int)(~(unsigned)(bp & 0xffffffffull));
                float tM = sigm_np(M);
                // sigmoid order provably follows logit order when
                // gap * e^{-max|logit|} > 1.6e-5 (deriv >= e^{-|x|}/4; 4x margin)
                float gap = M - m2;
                float mx = fmaxf(fabsf(M), fabsf(m2));
                if (!((gap * exp_np(-mx)) > 1.6e-5f)) {   // rare exact fallback
                    const float* cpe = cls + (size_t)b * NCLS * hw + y * W + x + e;
                    tM = sigm_np(cpe[0]); lab = 0;
                    for (int c = 1; c < NCLS; ++c) {
                        float t = sigm_np(cpe[(size_t)c * hw]);
                        if (t > tM) { tM = t; lab = c; }
                    }
                }
                float sv = tM * so[e];
                scv[e] = (sv >= 0.65f) ? sv : 0.0f;
                labv[e] = lab;
            }
            *(float4*)(sc + (size_t)b * NPRIOR + n0) =
                make_float4(scv[0], scv[1], scv[2], scv[3]);
            *(int4*)(labels + (size_t)b * NPRIOR + n0) =
                make_int4(labv[0], labv[1], labv[2], labv[3]);
        } else {
#pragma unroll
            for (int e = 0; e < 4; ++e) { scv[e] = 0.0f; labv[e] = 0; }
        }

        // per-block compaction: ballot prefix into private region (no atomics)
        u64* reg = keys_r + ((size_t)b * NBLK + blk) * 256;
        int base = 0;
#pragma unroll
        for (int e = 0; e < 4; ++e) {
            bool val = scv[e] > 0.0f;
            u64 mb = __ballot(val);
            if (val) {
                int pos = base + (int)__popcll(mb & ((1ull << lane) - 1ull));
                reg[pos] = ((u64)__float_as_uint(scv[e]) << 32) |
                           (unsigned)(~(unsigned)(n0 + e));
            }
            base += (int)__popcll(mb);
        }
        if (lane == 0) blkcnt[b * 64 + blk] = base;
    }
}

// ---- Kernel A2: concat block regions -> dense keys + cnts + zero rankbuf/maxbits ----
__global__ void __launch_bounds__(256) compact_k(
    const u64* __restrict__ keys_r, const int* __restrict__ blkcnt,
    u64* __restrict__ keys, int* __restrict__ cnts,
    int* __restrict__ rankbuf, int* __restrict__ maxbits)
{
    __shared__ int pref[NBLK + 1];
    int b = blockIdx.x, tid = threadIdx.x;
    if (tid == 0) {
        int s = 0;
        for (int k = 0; k < NBLK; ++k) { pref[k] = s; s += blkcnt[b * 64 + k]; }
        pref[NBLK] = s;
        cnts[b * CPAD] = s;          // s <= 8400 = CAP by construction
        maxbits[b * CPAD] = 0;
    }
    __syncthreads();
    int total = pref[NBLK];
    for (int k = 0; k < NBLK; ++k) {
        int beg = pref[k], cnum = pref[k + 1] - beg;
        for (int i = tid; i < cnum; i += 256)
            keys[(size_t)b * CAP + beg + i] = keys_r[((size_t)b * NBLK + k) * 256 + i];
    }
    for (int i = tid; i < total; i += 256) rankbuf[(size_t)b * CAP + i] = 0;
}

// ---- Kernel B1: 2D-tiled all-pairs partial rank (atomicAdd accumulate) ----
__global__ void __launch_bounds__(256) rank_part(
    const u64* __restrict__ keys, const int* __restrict__ cnts,
    int* __restrict__ rankbuf)
{
    int b = blockIdx.y, tid = threadIdx.x;
    int cn = min(cnts[b * CPAD], CAP);
    int nt = (cn + 255) >> 8;
    int ntt = nt * nt;
    const u64* keyimg = keys + (size_t)b * CAP;
    int lane = tid & 63;

    for (int t = blockIdx.x; t < ntt; t += gridDim.x) {
        int it = t / nt, jt = t - it * nt;
        int i = it * 256 + tid;
        u64 ki = (i < cn) ? keyimg[i] : ~0ull;
        int rank = 0;
        int jbase = jt * 256;
        int jend = min(jbase + 256, cn);
        for (int jb = jbase; jb < jend; jb += 64) {
            int j = jb + lane;
            u64 kv = (j < cn) ? keyimg[j] : 0ull;
            unsigned lo = (unsigned)kv, hi = (unsigned)(kv >> 32);
            int lim = jend - jb;
#pragma unroll
            for (int l = 0; l < 64; ++l) {
                unsigned jlo = __builtin_amdgcn_readlane(lo, l);
                unsigned jhi = __builtin_amdgcn_readlane(hi, l);
                u64 kj = ((u64)jhi << 32) | jlo;
                rank += (l < lim && kj > ki) ? 1 : 0;
            }
        }
        if (i < cn && rank > 0) atomicAdd(&rankbuf[(size_t)b * CAP + i], rank);
    }
}

// ---- Kernel B2: scatter by rank + decode + housekeeping ----
__global__ void __launch_bounds__(256) scatter_k(
    const u64* __restrict__ keys, const int* __restrict__ cnts,
    const int* __restrict__ rankbuf,
    const float* __restrict__ sc, const int* __restrict__ labels,
    const float* __restrict__ bb0, const float* __restrict__ bb1, const float* __restrict__ bb2,
    float4* __restrict__ sel_box, float* __restrict__ sel_score,
    int* __restrict__ sel_label, int* __restrict__ maxbits, u64* __restrict__ vmask)
{
#pragma clang fp contract(off)
    __shared__ float redbuf[256];
    int b = blockIdx.y, chunk = blockIdx.x, tid = threadIdx.x;
    int cn = min(cnts[b * CPAD], CAP);
    int base = chunk * 256;
    if (chunk != 0 && base >= cn) return;   // housekeeping lives in chunk 0

    const u64* keyimg = keys + (size_t)b * CAP;
    const int* labb = labels + (size_t)b * NPRIOR;
    const float* scb = sc + (size_t)b * NPRIOR;

    int i = base + tid;
    float lmax = 0.0f;
    if (i < cn) {
        int rank = rankbuf[(size_t)b * CAP + i];
        if (rank < KTOP) {
            u64 ki = keyimg[i];
            unsigned n = ~(unsigned)(ki & 0xffffffffull);
            float s = __uint_as_float((unsigned)(ki >> 32));
            float4 bx = decode32(b, (int)n, bb0, bb1, bb2);
            sel_box[(size_t)b * 1024 + rank] = bx;
            sel_score[(size_t)b * 1024 + rank] = s;
            sel_label[(size_t)b * 1024 + rank] = labb[n];
            lmax = fmaxf(fmaxf(fabsf(bx.x), fabsf(bx.y)),
                         fmaxf(fabsf(bx.z), fabsf(bx.w)));
        }
    }

    if (chunk == 0) {
        if (cn < KTOP && tid == 0) {   // rare fill path
            float lm = 0.0f;
            int r = cn;
            for (int n = 0; n < NPRIOR && r < KTOP; ++n) {
                if (scb[n] == 0.0f) {
                    float4 bx = decode32(b, n, bb0, bb1, bb2);
                    sel_box[(size_t)b * 1024 + r] = bx;
                    sel_score[(size_t)b * 1024 + r] = 0.0f;
                    sel_label[(size_t)b * 1024 + r] = labb[n];
                    lm = fmaxf(lm, fmaxf(fmaxf(fabsf(bx.x), fabsf(bx.y)),
                                         fmaxf(fabsf(bx.z), fabsf(bx.w))));
                    ++r;
                }
            }
            lmax = fmaxf(lmax, lm);
        }
        if (tid < 24) {   // padding rows 1000..1023
            sel_box[(size_t)b * 1024 + 1000 + tid] = make_float4(0.f, 0.f, 0.f, 0.f);
            sel_score[(size_t)b * 1024 + 1000 + tid] = 0.0f;
            sel_label[(size_t)b * 1024 + 1000 + tid] = 0;
        }
        if (tid < 16) {   // vmask closed form
            int vc = min(cn, KTOP);
            int lo = tid * 64;
            u64 m;
            if (vc >= lo + 64)      m = ~0ull;
            else if (vc <= lo)      m = 0ull;
            else                    m = (1ull << (vc - lo)) - 1ull;
            vmask[b * 16 + tid] = m;
        }
    }

    redbuf[tid] = lmax;
    __syncthreads();
    for (int off = 128; off > 0; off >>= 1) {
        if (tid < off) redbuf[tid] = fmaxf(redbuf[tid], redbuf[tid + off]);
        __syncthreads();
    }
    if (tid == 0) atomicMax(&maxbits[b * CPAD], __float_as_int(redbuf[0]));
}

// ---- Kernel C: ballot-free suppression bitmask, per-lane column ownership ----
__global__ void __launch_bounds__(256) build_mask_T(
    const float4* __restrict__ sel_box, const int* __restrict__ sel_label,
    const int* __restrict__ maxbits, u64* __restrict__ Cmask)
{
#pragma clang fp contract(off)
    __shared__ float4 obr[256];
    __shared__ float arr[256];
    int b = blockIdx.y;
    int cg = blockIdx.x & 15, rgq = blockIdx.x >> 4;
    if (rgq * 4 > cg) return;
    int tid = threadIdx.x, wave = tid >> 6, lane = tid & 63;
    float mc = __int_as_float(maxbits[b * CPAD]) + 1.0f;

    {
        int row = rgq * 256 + tid;
        float4 v = sel_box[(size_t)b * 1024 + row];
        float off = (float)sel_label[(size_t)b * 1024 + row] * mc;
        v.x += off; v.y += off; v.z += off; v.w += off;
        obr[tid] = v;
        arr[tid] = (v.z - v.x) * (v.w - v.y);
    }
    int col = cg * 64 + lane;
    float4 a = sel_box[(size_t)b * 1024 + col];
    float offc = (float)sel_label[(size_t)b * 1024 + col] * mc;
    a.x += offc; a.y += offc; a.z += offc; a.w += offc;
    float ac = (a.z - a.x) * (a.w - a.y);
    __syncthreads();

    int rg = rgq * 4 + wave;
    if (rg > cg) return;
    u64 bits = 0;
    int rowbase = rg * 64;
#pragma unroll 8
    for (int r = 0; r < 64; ++r) {
        int row = rowbase + r;
        float4 rb = obr[wave * 64 + r];
        float ra = arr[wave * 64 + r];
        bool pred = false;
        if (row < col && row < KTOP && col < KTOP) {
            float tlx = fmaxf(rb.x, a.x), tly = fmaxf(rb.y, a.y);
            float brx = fminf(rb.z, a.z), bry = fminf(rb.w, a.w);
            float w = fmaxf(brx - tlx, 0.0f), h = fmaxf(bry - tly, 0.0f);
            float inter = w * h;
            float uni = (ra + ac) - inter;
            float iou = inter / (uni + 1e-6f);
            pred = iou > 0.65f;
        }
        bits |= pred ? (1ull << r) : 0ull;
    }
    Cmask[((size_t)b * 16 + rg) * 1024 + col] = bits;
}

// ---- Kernel D: ballot-fixpoint greedy NMS + output ----
__global__ void __launch_bounds__(64) nms_fixpoint_write(
    const u64* __restrict__ Cmask, const u64* __restrict__ vmask,
    const float4* __restrict__ sel_box, const float* __restrict__ sel_score,
    const int* __restrict__ sel_label, float* __restrict__ out)
{
    int b = blockIdx.x, lane = threadIdx.x;
    const u64* Cimg = Cmask + (size_t)b * 16 * 1024;
    u64 Khist[16];
#pragma unroll
    for (int g = 0; g < 16; ++g) {
        int col = g * 64 + lane;
        bool supp = false;
#pragma unroll
        for (int gp = 0; gp < g; ++gp)
            supp |= (Cimg[(size_t)gp * 1024 + col] & Khist[gp]) != 0ull;
        u64 V = vmask[b * 16 + g] & ~__ballot(supp);
        u64 T = Cimg[(size_t)g * 1024 + col];
        u64 K = V;
        for (int it = 0; it < 64; ++it) {
            u64 Knew = V & ~__ballot((T & K) != 0ull);
            if (Knew == K) break;
            K = Knew;
        }
        Khist[g] = K;
    }

    const size_t selo = (size_t)b * 1024;
    float* lab_o = out + (size_t)NB * KTOP * 5;
    float* keep_o = lab_o + (size_t)NB * KTOP;
#pragma unroll
    for (int g = 0; g < 16; ++g) {
        int k = g * 64 + lane;
        if (k >= KTOP) break;
        bool fin = (Khist[g] >> lane) & 1ull;
        float4 bx = sel_box[selo + k];
        float s = sel_score[selo + k];
        int lb = sel_label[selo + k];
        size_t o5 = ((size_t)b * KTOP + k) * 5;
        out[o5 + 0] = fin ? bx.x : 0.0f;
        out[o5 + 1] = fin ? bx.y : 0.0f;
        out[o5 + 2] = fin ? bx.z : 0.0f;
        out[o5 + 3] = fin ? bx.w : 0.0f;
        out[o5 + 4] = fin ? s : 0.0f;
        lab_o[b * KTOP + k] = fin ? (float)lb : -1.0f;
        keep_o[b * KTOP + k] = fin ? 1.0f : 0.0f;
    }
}

extern "C" void kernel_launch(void* const* d_in, const int* in_sizes, int n_in,
                              void* d_out, int out_size, void* d_ws, size_t ws_size,
                              hipStream_t stream) {
    const float* cls0 = (const float*)d_in[0];
    const float* cls1 = (const float*)d_in[1];
    const float* cls2 = (const float*)d_in[2];
    const float* bb0  = (const float*)d_in[3];
    const float* bb1  = (const float*)d_in[4];
    const float* bb2  = (const float*)d_in[5];
    const float* ob0  = (const float*)d_in[6];
    const float* ob1  = (const float*)d_in[7];
    const float* ob2  = (const float*)d_in[8];
    float* out = (float*)d_out;

    char* w = (char*)d_ws;
    size_t used = 0;
    auto alloc = [&](size_t bytes) -> void* {
        void* p = (void*)(w + used);
        used += (bytes + 255) & ~(size_t)255;
        return p;
    };
    float* sc        = (float*)alloc((size_t)NB * NPRIOR * 4);
    int* labels      = (int*)alloc((size_t)NB * NPRIOR * 4);
    u64* keys_r      = (u64*)alloc((size_t)NB * NBLK * 256 * 8);
    int* blkcnt      = (int*)alloc((size_t)NB * 64 * 4);
    u64* keys        = (u64*)alloc((size_t)NB * CAP * 8);
    int* cnts_mb     = (int*)alloc((size_t)2 * NB * CPAD * 4);   // cnts | maxbits
    int* rankbuf     = (int*)alloc((size_t)NB * CAP * 4);
    float4* sel_box  = (float4*)alloc((size_t)NB * 1024 * 16);
    float* sel_score = (float*)alloc((size_t)NB * 1024 * 4);
    int* sel_label   = (int*)alloc((size_t)NB * 1024 * 4);
    u64* vmask       = (u64*)alloc((size_t)NB * 16 * 8);
    u64* Cmask       = (u64*)alloc((size_t)NB * 16 * 1024 * 8);

    if (used > ws_size) return;   // OOB-write guard

    int* cnts = cnts_mb;
    int* maxbits = cnts_mb + NB * CPAD;

    score_fused<<<dim3(NBLK, NB), 256, 0, stream>>>(
        cls0, cls1, cls2, ob0, ob1, ob2, sc, labels, keys_r, blkcnt);
    compact_k<<<NB, 256, 0, stream>>>(
        keys_r, blkcnt, keys, cnts, rankbuf, maxbits);
    rank_part<<<dim3(64, NB), 256, 0, stream>>>(keys, cnts, rankbuf);
    scatter_k<<<dim3((CAP + 255) / 256, NB), 256, 0, stream>>>(
        keys, cnts, rankbuf, sc, labels, bb0, bb1, bb2,
        sel_box, sel_score, sel_label, maxbits, vmask);
    build_mask_T<<<dim3(64, NB), 256, 0, stream>>>(sel_box, sel_label, maxbits, Cmask);
    nms_fixpoint_write<<<NB, 64, 0, stream>>>(
        Cmask, vmask, sel_box, sel_score, sel_label, out);
}

// Round 17
// 117.750 us; speedup vs baseline: 1.3187x; 1.2741x over previous
//
#include <hip/hip_runtime.h>
#include <stdint.h>

#define NPRIOR 8400
#define NB 32
#define NCLS 80
#define KTOP 1000
#define CAP 8400   // worst-case candidates
#define CPAD 16    // ints per counter slot (64B)

typedef unsigned long long u64;

// Bit-exact replica of numpy's float32 SIMD exp (Cephes-style, FMA path).
__device__ __forceinline__ float exp_np(float x) {
#pragma clang fp contract(off)
    if (x > 88.72283935546875f) return __builtin_huge_valf();
    if (x < -87.3365478515625f) return 0.0f;
    float q = rintf(x * 1.442695040f);
    float r = fmaf(q, -6.93145752e-1f, x);
    r = fmaf(q, -1.42860677e-6f, r);
    float p = fmaf(1.9875691500e-4f, r, 1.3981999507e-3f);
    p = fmaf(p, r, 8.3334519073e-3f);
    p = fmaf(p, r, 4.1665795894e-2f);
    p = fmaf(p, r, 1.6666665459e-1f);
    p = fmaf(p, r, 5.0000001201e-1f);
    float r2 = r * r;
    p = fmaf(p, r2, r);
    p = p + 1.0f;
    return ldexpf(p, (int)q);
}
__device__ __forceinline__ float sigm_np(float x) {
#pragma clang fp contract(off)
    float t = exp_np(-x);
    return 1.0f / (1.0f + t);
}

__device__ __forceinline__ void level_of(int n, int& W, int& s, int& loc) {
    if (n < 6400)      { W = 80; s = 8;  loc = n; }
    else if (n < 8000) { W = 40; s = 16; loc = n - 6400; }
    else               { W = 20; s = 32; loc = n - 8000; }
}

__device__ float4 decode32(int b, int n,
                           const float* bb0, const float* bb1, const float* bb2) {
#pragma clang fp contract(off)
    int W, s, loc; level_of(n, W, s, loc);
    const float* bb = (s == 8) ? bb0 : (s == 16) ? bb1 : bb2;
    int hw = W * W;
    int y = loc / W, x = loc - y * W;
    const float* bp = bb + (size_t)b * 4 * hw + y * W + x;
    float fs = (float)s;
    float cx = (float)x * fs, cy = (float)y * fs;
    float xc = bp[0] * fs + cx;
    float yc = bp[hw] * fs + cy;
    float wv = exp_np(bp[2 * hw]) * fs;
    float hv = exp_np(bp[3 * hw]) * fs;
    float wv2 = wv * 0.5f, hv2 = hv * 0.5f;
    float4 r;
    r.x = xc - wv2;
    r.y = yc - hv2;
    r.z = xc + wv2;
    r.w = yc + hv2;
    return r;
}

// ---- init: zero padded counters (cnts | maxbits), 64 ints total ----
__global__ void __launch_bounds__(64) init_k(int* __restrict__ cnts_mb) {
    cnts_mb[threadIdx.x * CPAD] = 0;   // t<32: cnts[b]; t>=32: maxbits[b-32]
}

// ---- Kernel A: flat per-prior score, depth-8 prefetched class scan ----
// One thread = one prior; 80 scalar loads in explicit 8-deep batches so the
// loads pipeline regardless of scheduler (round-16 lesson: VGPR24 serialized).
__global__ void __launch_bounds__(256) score_k(
    const float* __restrict__ cls0, const float* __restrict__ cls1, const float* __restrict__ cls2,
    const float* __restrict__ ob0,  const float* __restrict__ ob1,  const float* __restrict__ ob2,
    float* __restrict__ sc, int* __restrict__ labels,
    u64* __restrict__ keys, int* __restrict__ cnts, int* __restrict__ rankbuf)
{
#pragma clang fp contract(off)
    int b = blockIdx.y;
    int n = blockIdx.x * 256 + threadIdx.x;
    bool nvalid = (n < NPRIOR);
    int nc = nvalid ? n : NPRIOR - 1;            // clamp for safe addresses
    int W, s, loc; level_of(nc, W, s, loc);
    const float* cls = (s == 8) ? cls0 : (s == 16) ? cls1 : cls2;
    const float* ob  = (s == 8) ? ob0  : (s == 16) ? ob1  : ob2;
    int hw = W * W;
    int y = loc / W, x = loc - y * W;
    const float* cp = cls + (size_t)b * NCLS * hw + y * W + x;

    // logit first-max / second-max / argmax, 8 loads in flight per batch
    float M = -3.4e38f, S2 = -3.4e38f;
    int I = 0;
    for (int cb = 0; cb < NCLS; cb += 8) {
        float buf[8];
#pragma unroll
        for (int k = 0; k < 8; ++k) buf[k] = cp[(size_t)(cb + k) * hw];
#pragma unroll
        for (int k = 0; k < 8; ++k) {
            float l = buf[k];
            if (l > M) { S2 = M; M = l; I = cb + k; }
            else       { S2 = fmaxf(S2, l); }
        }
    }

    float tM = sigm_np(M);
    int lab = I;
    // sigmoid order provably follows logit order when
    // gap * e^{-max|logit|} > 1.6e-5 (deriv >= e^{-|x|}/4; err < 1e-6, 4x margin)
    float gap = M - S2;
    float mx = fmaxf(fabsf(M), fabsf(S2));
    if (!((gap * exp_np(-mx)) > 1.6e-5f)) {      // rare exact fallback
        tM = -1.0f; lab = 0;
        for (int c = 0; c < NCLS; ++c) {
            float t = sigm_np(cp[(size_t)c * hw]);
            if (t > tM) { tM = t; lab = c; }
        }
    }
    float sObj = sigm_np(ob[(size_t)b * hw + y * W + x]);
    float score = tM * sObj;
    float scv = (score >= 0.65f) ? score : 0.0f;
    if (nvalid) {
        sc[(size_t)b * NPRIOR + n] = scv;
        labels[(size_t)b * NPRIOR + n] = lab;
    }

    // wave-aggregated compaction (order-free; ranking restores stable order)
    int lane = threadIdx.x & 63;
    bool val = nvalid && (scv > 0.0f);
    u64 mb = __ballot(val);
    if (mb) {                                    // wave-uniform branch
        int lead = (int)__builtin_ctzll(mb);
        int base = 0;
        if (lane == lead) base = atomicAdd(&cnts[b * CPAD], (int)__popcll(mb));
        base = __shfl(base, lead);
        if (val) {
            int pos = base + (int)__popcll(mb & ((1ull << lane) - 1ull));
            keys[(size_t)b * CAP + pos] =
                ((u64)__float_as_uint(scv) << 32) | (unsigned)(~(unsigned)n);
            rankbuf[(size_t)b * CAP + pos] = 0;  // no memset needed
        }
    }
}

// ---- Kernel B1: 2D-tiled all-pairs partial rank (atomicAdd accumulate) ----
__global__ void __launch_bounds__(256) rank_part(
    const u64* __restrict__ keys, const int* __restrict__ cnts,
    int* __restrict__ rankbuf)
{
    int b = blockIdx.y, tid = threadIdx.x;
    int cn = min(cnts[b * CPAD], CAP);
    int nt = (cn + 255) >> 8;
    int ntt = nt * nt;
    const u64* keyimg = keys + (size_t)b * CAP;
    int lane = tid & 63;

    for (int t = blockIdx.x; t < ntt; t += gridDim.x) {
        int it = t / nt, jt = t - it * nt;
        int i = it * 256 + tid;
        u64 ki = (i < cn) ? keyimg[i] : ~0ull;
        int rank = 0;
        int jbase = jt * 256;
        int jend = min(jbase + 256, cn);
        for (int jb = jbase; jb < jend; jb += 64) {
            int j = jb + lane;
            u64 kv = (j < cn) ? keyimg[j] : 0ull;
            unsigned lo = (unsigned)kv, hi = (unsigned)(kv >> 32);
            int lim = jend - jb;
#pragma unroll
            for (int l = 0; l < 64; ++l) {
                unsigned jlo = __builtin_amdgcn_readlane(lo, l);
                unsigned jhi = __builtin_amdgcn_readlane(hi, l);
                u64 kj = ((u64)jhi << 32) | jlo;
                rank += (l < lim && kj > ki) ? 1 : 0;
            }
        }
        if (i < cn && rank > 0) atomicAdd(&rankbuf[(size_t)b * CAP + i], rank);
    }
}

// ---- Kernel B2: scatter by rank + decode + housekeeping ----
__global__ void __launch_bounds__(256) scatter_k(
    const u64* __restrict__ keys, const int* __restrict__ cnts,
    const int* __restrict__ rankbuf,
    const float* __restrict__ sc, const int* __restrict__ labels,
    const float* __restrict__ bb0, const float* __restrict__ bb1, const float* __restrict__ bb2,
    float4* __restrict__ sel_box, float* __restrict__ sel_score,
    int* __restrict__ sel_label, int* __restrict__ maxbits, u64* __restrict__ vmask)
{
#pragma clang fp contract(off)
    __shared__ float redbuf[256];
    int b = blockIdx.y, chunk = blockIdx.x, tid = threadIdx.x;
    int cn = min(cnts[b * CPAD], CAP);
    int base = chunk * 256;
    if (chunk != 0 && base >= cn) return;   // housekeeping lives in chunk 0

    const u64* keyimg = keys + (size_t)b * CAP;
    const int* labb = labels + (size_t)b * NPRIOR;
    const float* scb = sc + (size_t)b * NPRIOR;

    int i = base + tid;
    float lmax = 0.0f;
    if (i < cn) {
        int rank = rankbuf[(size_t)b * CAP + i];
        if (rank < KTOP) {
            u64 ki = keyimg[i];
            unsigned n = ~(unsigned)(ki & 0xffffffffull);
            float s = __uint_as_float((unsigned)(ki >> 32));
            float4 bx = decode32(b, (int)n, bb0, bb1, bb2);
            sel_box[(size_t)b * 1024 + rank] = bx;
            sel_score[(size_t)b * 1024 + rank] = s;
            sel_label[(size_t)b * 1024 + rank] = labb[n];
            lmax = fmaxf(fmaxf(fabsf(bx.x), fabsf(bx.y)),
                         fmaxf(fabsf(bx.z), fabsf(bx.w)));
        }
    }

    if (chunk == 0) {
        if (cn < KTOP && tid == 0) {   // rare fill path
            float lm = 0.0f;
            int r = cn;
            for (int n = 0; n < NPRIOR && r < KTOP; ++n) {
                if (scb[n] == 0.0f) {
                    float4 bx = decode32(b, n, bb0, bb1, bb2);
                    sel_box[(size_t)b * 1024 + r] = bx;
                    sel_score[(size_t)b * 1024 + r] = 0.0f;
                    sel_label[(size_t)b * 1024 + r] = labb[n];
                    lm = fmaxf(lm, fmaxf(fmaxf(fabsf(bx.x), fabsf(bx.y)),
                                         fmaxf(fabsf(bx.z), fabsf(bx.w))));
                    ++r;
                }
            }
            lmax = fmaxf(lmax, lm);
        }
        if (tid < 24) {   // padding rows 1000..1023
            sel_box[(size_t)b * 1024 + 1000 + tid] = make_float4(0.f, 0.f, 0.f, 0.f);
            sel_score[(size_t)b * 1024 + 1000 + tid] = 0.0f;
            sel_label[(size_t)b * 1024 + 1000 + tid] = 0;
        }
        if (tid < 16) {   // vmask closed form
            int vc = min(cn, KTOP);
            int lo = tid * 64;
            u64 m;
            if (vc >= lo + 64)      m = ~0ull;
            else if (vc <= lo)      m = 0ull;
            else                    m = (1ull << (vc - lo)) - 1ull;
            vmask[b * 16 + tid] = m;
        }
    }

    redbuf[tid] = lmax;
    __syncthreads();
    for (int off = 128; off > 0; off >>= 1) {
        if (tid < off) redbuf[tid] = fmaxf(redbuf[tid], redbuf[tid + off]);
        __syncthreads();
    }
    if (tid == 0) atomicMax(&maxbits[b * CPAD], __float_as_int(redbuf[0]));
}

// ---- Kernel C: ballot-free suppression bitmask, per-lane column ownership ----
__global__ void __launch_bounds__(256) build_mask_T(
    const float4* __restrict__ sel_box, const int* __restrict__ sel_label,
    const int* __restrict__ maxbits, u64* __restrict__ Cmask)
{
#pragma clang fp contract(off)
    __shared__ float4 obr[256];
    __shared__ float arr[256];
    int b = blockIdx.y;
    int cg = blockIdx.x & 15, rgq = blockIdx.x >> 4;
    if (rgq * 4 > cg) return;
    int tid = threadIdx.x, wave = tid >> 6, lane = tid & 63;
    float mc = __int_as_float(maxbits[b * CPAD]) + 1.0f;

    {
        int row = rgq * 256 + tid;
        float4 v = sel_box[(size_t)b * 1024 + row];
        float off = (float)sel_label[(size_t)b * 1024 + row] * mc;
        v.x += off; v.y += off; v.z += off; v.w += off;
        obr[tid] = v;
        arr[tid] = (v.z - v.x) * (v.w - v.y);
    }
    int col = cg * 64 + lane;
    float4 a = sel_box[(size_t)b * 1024 + col];
    float offc = (float)sel_label[(size_t)b * 1024 + col] * mc;
    a.x += offc; a.y += offc; a.z += offc; a.w += offc;
    float ac = (a.z - a.x) * (a.w - a.y);
    __syncthreads();

    int rg = rgq * 4 + wave;
    if (rg > cg) return;
    u64 bits = 0;
    int rowbase = rg * 64;
#pragma unroll 8
    for (int r = 0; r < 64; ++r) {
        int row = rowbase + r;
        float4 rb = obr[wave * 64 + r];
        float ra = arr[wave * 64 + r];
        bool pred = false;
        if (row < col && row < KTOP && col < KTOP) {
            float tlx = fmaxf(rb.x, a.x), tly = fmaxf(rb.y, a.y);
            float brx = fminf(rb.z, a.z), bry = fminf(rb.w, a.w);
            float w = fmaxf(brx - tlx, 0.0f), h = fmaxf(bry - tly, 0.0f);
            float inter = w * h;
            float uni = (ra + ac) - inter;
            float iou = inter / (uni + 1e-6f);
            pred = iou > 0.65f;
        }
        bits |= pred ? (1ull << r) : 0ull;
    }
    Cmask[((size_t)b * 16 + rg) * 1024 + col] = bits;
}

// ---- Kernel D: ballot-fixpoint greedy NMS + output ----
__global__ void __launch_bounds__(64) nms_fixpoint_write(
    const u64* __restrict__ Cmask, const u64* __restrict__ vmask,
    const float4* __restrict__ sel_box, const float* __restrict__ sel_score,
    const int* __restrict__ sel_label, float* __restrict__ out)
{
    int b = blockIdx.x, lane = threadIdx.x;
    const u64* Cimg = Cmask + (size_t)b * 16 * 1024;
    u64 Khist[16];
#pragma unroll
    for (int g = 0; g < 16; ++g) {
        int col = g * 64 + lane;
        bool supp = false;
#pragma unroll
        for (int gp = 0; gp < g; ++gp)
            supp |= (Cimg[(size_t)gp * 1024 + col] & Khist[gp]) != 0ull;
        u64 V = vmask[b * 16 + g] & ~__ballot(supp);
        u64 T = Cimg[(size_t)g * 1024 + col];
        u64 K = V;
        for (int it = 0; it < 64; ++it) {
            u64 Knew = V & ~__ballot((T & K) != 0ull);
            if (Knew == K) break;
            K = Knew;
        }
        Khist[g] = K;
    }

    const size_t selo = (size_t)b * 1024;
    float* lab_o = out + (size_t)NB * KTOP * 5;
    float* keep_o = lab_o + (size_t)NB * KTOP;
#pragma unroll
    for (int g = 0; g < 16; ++g) {
        int k = g * 64 + lane;
        if (k >= KTOP) break;
        bool fin = (Khist[g] >> lane) & 1ull;
        float4 bx = sel_box[selo + k];
        float s = sel_score[selo + k];
        int lb = sel_label[selo + k];
        size_t o5 = ((size_t)b * KTOP + k) * 5;
        out[o5 + 0] = fin ? bx.x : 0.0f;
        out[o5 + 1] = fin ? bx.y : 0.0f;
        out[o5 + 2] = fin ? bx.z : 0.0f;
        out[o5 + 3] = fin ? bx.w : 0.0f;
        out[o5 + 4] = fin ? s : 0.0f;
        lab_o[b * KTOP + k] = fin ? (float)lb : -1.0f;
        keep_o[b * KTOP + k] = fin ? 1.0f : 0.0f;
    }
}

extern "C" void kernel_launch(void* const* d_in, const int* in_sizes, int n_in,
                              void* d_out, int out_size, void* d_ws, size_t ws_size,
                              hipStream_t stream) {
    const float* cls0 = (const float*)d_in[0];
    const float* cls1 = (const float*)d_in[1];
    const float* cls2 = (const float*)d_in[2];
    const float* bb0  = (const float*)d_in[3];
    const float* bb1  = (const float*)d_in[4];
    const float* bb2  = (const float*)d_in[5];
    const float* ob0  = (const float*)d_in[6];
    const float* ob1  = (const float*)d_in[7];
    const float* ob2  = (const float*)d_in[8];
    float* out = (float*)d_out;

    char* w = (char*)d_ws;
    size_t used = 0;
    auto alloc = [&](size_t bytes) -> void* {
        void* p = (void*)(w + used);
        used += (bytes + 255) & ~(size_t)255;
        return p;
    };
    float* sc        = (float*)alloc((size_t)NB * NPRIOR * 4);
    int* labels      = (int*)alloc((size_t)NB * NPRIOR * 4);
    u64* keys        = (u64*)alloc((size_t)NB * CAP * 8);
    int* cnts_mb     = (int*)alloc((size_t)2 * NB * CPAD * 4);   // cnts | maxbits
    int* rankbuf     = (int*)alloc((size_t)NB * CAP * 4);
    float4* sel_box  = (float4*)alloc((size_t)NB * 1024 * 16);
    float* sel_score = (float*)alloc((size_t)NB * 1024 * 4);
    int* sel_label   = (int*)alloc((size_t)NB * 1024 * 4);
    u64* vmask       = (u64*)alloc((size_t)NB * 16 * 8);
    u64* Cmask       = (u64*)alloc((size_t)NB * 16 * 1024 * 8);

    if (used > ws_size) return;   // OOB-write guard

    int* cnts = cnts_mb;
    int* maxbits = cnts_mb + NB * CPAD;

    init_k<<<1, 64, 0, stream>>>(cnts_mb);
    score_k<<<dim3((NPRIOR + 255) / 256, NB), 256, 0, stream>>>(
        cls0, cls1, cls2, ob0, ob1, ob2, sc, labels, keys, cnts, rankbuf);
    rank_part<<<dim3(64, NB), 256, 0, stream>>>(keys, cnts, rankbuf);
    scatter_k<<<dim3((CAP + 255) / 256, NB), 256, 0, stream>>>(
        keys, cnts, rankbuf, sc, labels, bb0, bb1, bb2,
        sel_box, sel_score, sel_label, maxbits, vmask);
    build_mask_T<<<dim3(64, NB), 256, 0, stream>>>(sel_box, sel_label, maxbits, Cmask);
    nms_fixpoint_write<<<NB, 64, 0, stream>>>(
        Cmask, vmask, sel_box, sel_score, sel_label, out);
}